// Round 10
// baseline (329.181 us; speedup 1.0000x reference)
//
#include <hip/hip_runtime.h>
#include <hip/hip_bf16.h>
#include <cstdint>
#include <cstddef>

#define N_NODES 50000
#define N_EDGES 640000
#define ROWS    100000   // B * N_NODES
#define HID     128
#define OUTD    16
#define AGG_BLOCKS 2048
#define MID_BLOCKS 32
#define SCAN_BLOCKS 196  // ceil(50000/256)
#define GEMM_BLOCKS 512
#define G2_BLOCKS   800           // 3200 waves >= 3125 pair-tiles -> 1 pair/wave
#define GEMM_TILES  (ROWS / 16)   // 6250
#define PAIR_TILES  (N_NODES / 16) // 3125 (batch-0 tile + its batch-1 twin)
#define EG_BLOCKS   3500          // fused edge(2500) + gemm1(1000), 5:2 interleave
#define EG_GEMM_WAVES 4000        // 1000 blocks * 4 waves

// ---------- types ----------
typedef __attribute__((ext_vector_type(8))) uint16_t ushort8;
typedef __attribute__((ext_vector_type(8))) __bf16   bf16x8;
typedef __attribute__((ext_vector_type(2))) __bf16   bf16x2;
typedef __attribute__((ext_vector_type(4))) float    floatx4;

union FragU { ushort8 u; bf16x8 b; };

// ---------- bf16 helpers ----------
__device__ __forceinline__ float bf_lo(uint32_t u){
  union { uint32_t u; float f; } c; c.u = u << 16; return c.f;
}
__device__ __forceinline__ float bf_hi(uint32_t u){
  union { uint32_t u; float f; } c; c.u = u & 0xffff0000u; return c.f;
}
__device__ __forceinline__ uint16_t f2bf(float f){   // RNE bit-twiddle (cold paths)
  union { float f; uint32_t u; } c; c.f = f;
  uint32_t u = c.u;
  uint32_t r = (u + 0x7fffu + ((u >> 16) & 1u)) >> 16;
  return (uint16_t)r;
}
// native-cast pack (hot paths): compiler emits packed cvt; RNE, bit-identical to f2bf
__device__ __forceinline__ uint32_t pkbf(float a, float b){
  union { bf16x2 v; uint32_t u; } c;
  c.v[0] = (__bf16)a; c.v[1] = (__bf16)b;
  return c.u;
}

// ---------- W pack (paired-column B-frag mapping), shared by initpack/prep2 ----------
// c-tile c, in-tile col m -> actual col (c>>1)*32 + 2m + (c&1)  (adjacent-col acc pairs)
__device__ __forceinline__ void pack_w(int t, const float* __restrict__ W,
                                       const float* sca /*LDS or null*/,
                                       uint16_t* __restrict__ WP){
  int L = t & 63;
  int s = (t >> 6) & 3;
  int c = t >> 8;
  int n = (c >> 1) * 32 + 2 * (L & 15) + (c & 1);
  int k0 = s * 32 + (L >> 4) * 8;
  ushort8 r;
#pragma unroll
  for (int j = 0; j < 8; j++){
    float w = W[(size_t)(k0 + j) * HID + n];
    if (sca) w *= sca[k0 + j];
    r[j] = f2bf(w);
  }
  *((ushort8*)(WP + (size_t)t * 8)) = r;
}

// ---------- launch 1: zero DC + zero cursor + pack W1 ----------
__global__ void k_initpack(unsigned long long* __restrict__ dc,
                           const float* __restrict__ W1, uint16_t* __restrict__ WP1,
                           unsigned int* __restrict__ cursor){
  int b = blockIdx.x;
  if (b < SCAN_BLOCKS){
    int i = b * 256 + threadIdx.x;
    if (i < N_NODES) dc[i] = 0ull;
  } else {
    if (b == SCAN_BLOCKS && threadIdx.x == 0) *cursor = 0u;
    pack_w((b - SCAN_BLOCKS) * 256 + threadIdx.x, W1, nullptr, WP1);
  }
}

// ---------- launch 2: fused edge-degree atomics + GEMM1 (independent, overlap; 5:2) ----------
// DC[i]: bits[63:44] = in-degree count, bits[43:0] = sum(w) in 2^20 fixed point.
// NOTE: launch_bounds min-waves MUST stay 2 — min 4 caps VGPR at 128 and spills wf[8][4]
// XW layout: PAIR-INTERLEAVED — u32 index = node*128 + p*2 + b (p = feature-pair 0..63).
__global__ __launch_bounds__(256, 2) void k_edge_gemm1(const int* __restrict__ ei,
                                                       const float* __restrict__ ewp,
                                                       unsigned long long* __restrict__ dc,
                                                       unsigned int* __restrict__ slot,
                                                       const float* __restrict__ X,
                                                       const uint16_t* __restrict__ WP,
                                                       uint16_t* __restrict__ Y){
  const int b = blockIdx.x;
  const int g = b % 7;
  if (g < 5){
    // ---- edge part: block eb handles 256 edges ----
    const int eb = (b / 7) * 5 + g;              // 0..2499
    const int e = eb * 256 + threadIdx.x;        // < 640000 exactly
    float w = expf(ewp[e]);
    int c = ei[N_EDGES + e];
    unsigned long long inc = (1ull << 44) | (unsigned long long)(w * 1048576.0f + 0.5f);
    unsigned long long old = atomicAdd(&dc[c], inc);
    slot[e] = (unsigned int)(old >> 44);
    return;
  }
  // ---- gemm1 part: bf16(x) @ W1' -> XW pair-interleaved, tile-pair per wave ----
  const int lane = threadIdx.x & 63;
  const int wid  = threadIdx.x >> 6;
  const int gw   = ((b / 7) * 2 + (g - 5)) * 4 + wid;   // 0..3999
  const int m    = lane & 15;
  const int kq   = lane >> 4;

  FragU wf[8][4];
#pragma unroll
  for (int c = 0; c < 8; c++)
#pragma unroll
    for (int s = 0; s < 4; s++)
      wf[c][s].u = *((const ushort8*)(WP + (size_t)(((c * 4 + s) * 64 + lane) * 8)));

  unsigned long long* Yq = (unsigned long long*)Y;
  for (int t = gw; t < PAIR_TILES; t += EG_GEMM_WAVES){
    const int nb = t * 16;                      // node rows nb..nb+15
    uint32_t pr0[16];
    // ---- batch 0 tile ----
    {
      FragU af[4];
#pragma unroll
      for (int s = 0; s < 4; s++){
        const float* p = X + (size_t)(nb + m) * HID + s * 32 + kq * 8;
        floatx4 f0 = *((const floatx4*)p);
        floatx4 f1 = *((const floatx4*)(p + 4));
#pragma unroll
        for (int j = 0; j < 4; j++){ af[s].b[j] = (__bf16)f0[j]; af[s].b[j + 4] = (__bf16)f1[j]; }
      }
      floatx4 acc[8];
#pragma unroll
      for (int c = 0; c < 8; c++) acc[c] = floatx4{0.f, 0.f, 0.f, 0.f};
#pragma unroll
      for (int s = 0; s < 4; s++)
#pragma unroll
        for (int c = 0; c < 8; c++)
          acc[c] = __builtin_amdgcn_mfma_f32_16x16x32_bf16(af[s].b, wf[c][s].b, acc[c], 0, 0, 0);
#pragma unroll
      for (int t4 = 0; t4 < 4; t4++)
#pragma unroll
        for (int i = 0; i < 4; i++)
          pr0[t4 * 4 + i] = pkbf(acc[2 * t4][i], acc[2 * t4 + 1][i]);
    }
    // ---- batch 1 tile (same nodes) + fused u64 store ----
    {
      FragU af[4];
#pragma unroll
      for (int s = 0; s < 4; s++){
        const float* p = X + (size_t)(N_NODES + nb + m) * HID + s * 32 + kq * 8;
        floatx4 f0 = *((const floatx4*)p);
        floatx4 f1 = *((const floatx4*)(p + 4));
#pragma unroll
        for (int j = 0; j < 4; j++){ af[s].b[j] = (__bf16)f0[j]; af[s].b[j + 4] = (__bf16)f1[j]; }
      }
      floatx4 acc[8];
#pragma unroll
      for (int c = 0; c < 8; c++) acc[c] = floatx4{0.f, 0.f, 0.f, 0.f};
#pragma unroll
      for (int s = 0; s < 4; s++)
#pragma unroll
        for (int c = 0; c < 8; c++)
          acc[c] = __builtin_amdgcn_mfma_f32_16x16x32_bf16(af[s].b, wf[c][s].b, acc[c], 0, 0, 0);
#pragma unroll
      for (int t4 = 0; t4 < 4; t4++)
#pragma unroll
        for (int i = 0; i < 4; i++){
          uint32_t pr1 = pkbf(acc[2 * t4][i], acc[2 * t4 + 1][i]);
          Yq[(size_t)(nb + kq * 4 + i) * 64 + t4 * 16 + m] =
              (unsigned long long)pr0[t4 * 4 + i] | ((unsigned long long)pr1 << 32);
        }
    }
  }
}

// ---------- launch 3: DC -> dinv + CSR range allocation (NO ordered scan needed) ----------
__global__ void k_alloc(const unsigned long long* __restrict__ dc,
                        unsigned long long* __restrict__ rp2,
                        float* __restrict__ dinv,
                        unsigned int* __restrict__ cursor){
  __shared__ int sd[256];
  __shared__ unsigned int sbase;
  const int tid = threadIdx.x;
  const int i = blockIdx.x * 256 + tid;
  int cnt = 0;
  if (i < N_NODES){
    unsigned long long v = dc[i];
    cnt = (int)(v >> 44);
    float deg = 1.0f + (float)((double)(v & ((1ull << 44) - 1)) * (1.0 / 1048576.0));
    dinv[i] = 1.0f / sqrtf(deg);
  }
  sd[tid] = cnt;
  __syncthreads();
  for (int off = 1; off < 256; off <<= 1){
    int t = (tid >= off) ? sd[tid - off] : 0;
    __syncthreads();
    sd[tid] += t;
    __syncthreads();
  }
  if (tid == 255) sbase = atomicAdd(cursor, (unsigned int)sd[255]);
  __syncthreads();
  if (i < N_NODES){
    unsigned int start = sbase + (unsigned int)(sd[tid] - cnt);
    rp2[i] = ((unsigned long long)(unsigned int)cnt << 32) | start;
  }
}

// ---------- launch 4: fill CSR with packed record (norm<<32 | src); slot known -> NO atomic ----------
__global__ void k_fill(const int* __restrict__ ei, const float* __restrict__ ewp,
                       const float* __restrict__ dinv, const unsigned int* __restrict__ slot,
                       const unsigned long long* __restrict__ rp2,
                       unsigned long long* __restrict__ edg){
  int e = blockIdx.x * 256 + threadIdx.x;
  if (e < N_EDGES){
    int r = ei[e];
    int c = ei[N_EDGES + e];
    float w = expf(ewp[e]);
    float nrm = dinv[r] * w * dinv[c];
    int p = (int)(unsigned int)rp2[c] + (int)slot[e];
    edg[p] = ((unsigned long long)__float_as_uint(nrm) << 32) | (unsigned int)r;
  }
}

// ---------- standalone GEMM2: bf16 H @ W2' -> XW pair-interleaved, tile-pair per wave ----------
__global__ __launch_bounds__(256, 2) void k_gemm2(const uint16_t* __restrict__ X,
                                                  const uint16_t* __restrict__ WP,
                                                  uint16_t* __restrict__ Y){
  const int lane = threadIdx.x & 63;
  const int wid  = threadIdx.x >> 6;
  const int gw   = blockIdx.x * 4 + wid;
  const int nw   = G2_BLOCKS * 4;
  const int m    = lane & 15;
  const int kq   = lane >> 4;

  FragU wf[8][4];
#pragma unroll
  for (int c = 0; c < 8; c++)
#pragma unroll
    for (int s = 0; s < 4; s++)
      wf[c][s].u = *((const ushort8*)(WP + (size_t)(((c * 4 + s) * 64 + lane) * 8)));

  unsigned long long* Yq = (unsigned long long*)Y;
  for (int t = gw; t < PAIR_TILES; t += nw){
    const int nb = t * 16;
    uint32_t pr0[16];
    // ---- batch 0 tile ----
    {
      FragU af[4];
#pragma unroll
      for (int s = 0; s < 4; s++)
        af[s].u = *((const ushort8*)(X + (size_t)(nb + m) * HID + s * 32 + kq * 8));
      floatx4 acc[8];
#pragma unroll
      for (int c = 0; c < 8; c++) acc[c] = floatx4{0.f, 0.f, 0.f, 0.f};
#pragma unroll
      for (int s = 0; s < 4; s++)
#pragma unroll
        for (int c = 0; c < 8; c++)
          acc[c] = __builtin_amdgcn_mfma_f32_16x16x32_bf16(af[s].b, wf[c][s].b, acc[c], 0, 0, 0);
#pragma unroll
      for (int t4 = 0; t4 < 4; t4++)
#pragma unroll
        for (int i = 0; i < 4; i++)
          pr0[t4 * 4 + i] = pkbf(acc[2 * t4][i], acc[2 * t4 + 1][i]);
    }
    // ---- batch 1 tile + fused u64 store ----
    {
      FragU af[4];
#pragma unroll
      for (int s = 0; s < 4; s++)
        af[s].u = *((const ushort8*)(X + (size_t)(N_NODES + nb + m) * HID + s * 32 + kq * 8));
      floatx4 acc[8];
#pragma unroll
      for (int c = 0; c < 8; c++) acc[c] = floatx4{0.f, 0.f, 0.f, 0.f};
#pragma unroll
      for (int s = 0; s < 4; s++)
#pragma unroll
        for (int c = 0; c < 8; c++)
          acc[c] = __builtin_amdgcn_mfma_f32_16x16x32_bf16(af[s].b, wf[c][s].b, acc[c], 0, 0, 0);
#pragma unroll
      for (int t4 = 0; t4 < 4; t4++)
#pragma unroll
        for (int i = 0; i < 4; i++){
          uint32_t pr1 = pkbf(acc[2 * t4][i], acc[2 * t4 + 1][i]);
          Yq[(size_t)(nb + kq * 4 + i) * 64 + t4 * 16 + m] =
              (unsigned long long)pr0[t4 * 4 + i] | ((unsigned long long)pr1 << 32);
        }
    }
  }
}

// ---------- MFMA classifier: out = h @ WcS + cvec (fp32 out) ----------
__global__ __launch_bounds__(256) void k_cls_mfma(const uint16_t* __restrict__ H,
                                                  const uint16_t* __restrict__ WPC,
                                                  const float* __restrict__ cvec,
                                                  float* __restrict__ out){
  const int lane = threadIdx.x & 63;
  const int wid  = threadIdx.x >> 6;
  const int gw   = blockIdx.x * 4 + wid;
  const int nw   = GEMM_BLOCKS * 4;
  const int m    = lane & 15;
  const int kq   = lane >> 4;

  FragU wf[4];
#pragma unroll
  for (int s = 0; s < 4; s++)
    wf[s].u = *((const ushort8*)(WPC + (size_t)((s * 64 + lane) * 8)));
  const float cv = cvec[m];

  for (int t = gw; t < GEMM_TILES; t += nw){
    const int row0 = t * 16;
    FragU af[4];
#pragma unroll
    for (int s = 0; s < 4; s++)
      af[s].u = *((const ushort8*)(H + (size_t)(row0 + m) * HID + s * 32 + kq * 8));
    floatx4 acc = floatx4{0.f, 0.f, 0.f, 0.f};
#pragma unroll
    for (int s = 0; s < 4; s++)
      acc = __builtin_amdgcn_mfma_f32_16x16x32_bf16(af[s].b, wf[s].b, acc, 0, 0, 0);
#pragma unroll
    for (int i = 0; i < 4; i++)
      out[(size_t)(row0 + kq * 4 + i) * OUTD + m] = acc[i] + cv;
  }
}

// ---------- aggregation: node per wave + 2-DEEP GATHER PIPELINE.
// While group g's FMAs run, group g+1's 8 gathers are already in flight (qA/qB
// double-buffer, phase-unrolled for static reg indexing). Record loads stay one
// group ahead as before (incl. cross-node). FMA order per node unchanged ->
// bitwise-identical output. VGPR budget: ~32 + 16 (2nd q set) < 64 cliff. ----------

#define STAGE_GROUP(Q, RLO, RHI, GS)                                                         \
  {                                                                                          \
    RLO = (uint32_t)rec; RHI = (uint32_t)(rec >> 32);                                        \
    const int rr_ = e1 - (GS);                                                               \
    if (rr_ >= 8){                                                                           \
      _Pragma("unroll")                                                                      \
      for (int u = 0; u < 8; u++)                                                            \
        Q[u] = Xq[(size_t)(uint32_t)__builtin_amdgcn_readlane((int)RLO, u) * 64 + lane];     \
    } else {                                                                                 \
      _Pragma("unroll")                                                                      \
      for (int u = 0; u < 8; u++)                                                            \
        if (u < rr_)                                                                         \
          Q[u] = Xq[(size_t)(uint32_t)__builtin_amdgcn_readlane((int)RLO, u) * 64 + lane];   \
    }                                                                                        \
    const int pe_ = ((GS) + 8 < e1) ? ((GS) + 8) : (more ? ne0 : -1);                        \
    if (pe_ >= 0){                                                                           \
      int a_ = pe_ + lu; if (a_ > N_EDGES - 1) a_ = N_EDGES - 1;                             \
      rec = edg[a_];                                                                         \
    }                                                                                        \
  }

#define COMPUTE_GROUP(Q, RHI, GS)                                                            \
  {                                                                                          \
    const int rr_ = e1 - (GS);                                                               \
    if (rr_ >= 8){                                                                           \
      _Pragma("unroll")                                                                      \
      for (int u = 0; u < 8; u++){                                                           \
        const float w_ = __uint_as_float((uint32_t)__builtin_amdgcn_readlane((int)RHI, u));  \
        const uint32_t g0_ = (uint32_t)Q[u], g1_ = (uint32_t)(Q[u] >> 32);                   \
        a0x = fmaf(w_, bf_lo(g0_), a0x); a0y = fmaf(w_, bf_hi(g0_), a0y);                    \
        a1x = fmaf(w_, bf_lo(g1_), a1x); a1y = fmaf(w_, bf_hi(g1_), a1y);                    \
        wsum += w_;                                                                          \
      }                                                                                      \
    } else {                                                                                 \
      _Pragma("unroll")                                                                      \
      for (int u = 0; u < 8; u++)                                                            \
        if (u < rr_){                                                                        \
          const float w_ = __uint_as_float((uint32_t)__builtin_amdgcn_readlane((int)RHI, u));\
          const uint32_t g0_ = (uint32_t)Q[u], g1_ = (uint32_t)(Q[u] >> 32);                 \
          a0x = fmaf(w_, bf_lo(g0_), a0x); a0y = fmaf(w_, bf_hi(g0_), a0y);                  \
          a1x = fmaf(w_, bf_lo(g1_), a1x); a1y = fmaf(w_, bf_hi(g1_), a1y);                  \
          wsum += w_;                                                                        \
        }                                                                                    \
    }                                                                                        \
  }

__global__ __launch_bounds__(256) void k_agg(const uint16_t* __restrict__ XW,
                                             const unsigned long long* __restrict__ rp2,
                                             const unsigned long long* __restrict__ edg,
                                             const float* __restrict__ dinv,
                                             const float* __restrict__ bias,
                                             const float* __restrict__ cvec,
                                             uint16_t* __restrict__ H,
                                             float* __restrict__ psum,
                                             float* __restrict__ pssq){
  __shared__ float lsum[128];
  __shared__ float lssq[128];
  const int tid = threadIdx.x;
  if (tid < 128){ lsum[tid] = 0.f; lssq[tid] = 0.f; }
  __syncthreads();

  const int lane = tid & 63;
  const int wid  = tid >> 6;
  const int gw   = blockIdx.x * 4 + wid;
  const int nw   = AGG_BLOCKS * 4;
  const unsigned long long* Xq = (const unsigned long long*)XW;  // [node][pair]: lo u32 = batch0, hi = batch1
  uint32_t* Hu = (uint32_t*)H;
  const int f0 = lane * 2;
  const float b0 = bias[f0], b1 = bias[f0 + 1];
  const float c0 = cvec ? cvec[f0] : 0.f;
  const float c1 = cvec ? cvec[f0 + 1] : 0.f;
  float ts0 = 0.f, ts1 = 0.f, tq0 = 0.f, tq1 = 0.f;
  const int lu = lane & 7;

  int node = gw;
  if (node < N_NODES){
    unsigned long long rc = rp2[node];
    int e0 = (int)(unsigned int)rc, e1 = e0 + (int)(rc >> 32);
    float di = dinv[node];
    unsigned long long sv = Xq[(size_t)node * 64 + lane];
    unsigned long long rec = 0ull;
    if (e0 < e1){
      int a = e0 + lu; if (a > N_EDGES - 1) a = N_EDGES - 1;
      rec = edg[a];
    }
    while (true){
      // prefetch next node's header while this node's edges stream
      const int nn = node + nw;
      const bool more = (nn < N_NODES);
      int ne0 = 0, ne1 = 0; float ndi = 0.f; unsigned long long nsv = 0ull;
      if (more){
        unsigned long long nrc = rp2[nn];
        ne0 = (int)(unsigned int)nrc; ne1 = ne0 + (int)(nrc >> 32);
        ndi = dinv[nn];
        nsv = Xq[(size_t)nn * 64 + lane];
      }

      const float sn = di * di;
      const uint32_t s0 = (uint32_t)sv, s1 = (uint32_t)(sv >> 32);
      float a0x = sn * bf_lo(s0), a0y = sn * bf_hi(s0);
      float a1x = sn * bf_lo(s1), a1y = sn * bf_hi(s1);
      float wsum = sn;

      unsigned long long qA[8], qB[8];
      uint32_t rloA = 0, rhiA = 0, rloB = 0, rhiB = 0;
      (void)rloA; (void)rloB;

      if (e0 < e1){
        // preamble: stage group 0 into qA (also prefetches rec for group 1 / next node)
        STAGE_GROUP(qA, rloA, rhiA, e0);
        int gs = e0;
        int phase = 0;
        while (gs < e1){
          const bool havenext = (gs + 8 < e1);
          if (phase == 0){
            if (havenext) STAGE_GROUP(qB, rloB, rhiB, gs + 8);
            COMPUTE_GROUP(qA, rhiA, gs);
          } else {
            if (havenext) STAGE_GROUP(qA, rloA, rhiA, gs + 8);
            COMPUTE_GROUP(qB, rhiB, gs);
          }
          phase ^= 1;
          gs += 8;
        }
      } else if (more){
        // zero-edge node: chain the rec prefetch for the next node
        int a = ne0 + lu; if (a > N_EDGES - 1) a = N_EDGES - 1;
        rec = edg[a];
      }

      // rank-1 BN-fold term + bias + relu
      a0x = fmaxf(fmaf(wsum, c0, a0x) + b0, 0.f); a0y = fmaxf(fmaf(wsum, c1, a0y) + b1, 0.f);
      a1x = fmaxf(fmaf(wsum, c0, a1x) + b0, 0.f); a1y = fmaxf(fmaf(wsum, c1, a1y) + b1, 0.f);
      Hu[(size_t)node * 64 + lane]             = pkbf(a0x, a0y);
      Hu[(size_t)(N_NODES + node) * 64 + lane] = pkbf(a1x, a1y);
      ts0 += a0x + a1x; ts1 += a0y + a1y;
      tq0 += a0x * a0x + a1x * a1x; tq1 += a0y * a0y + a1y * a1y;

      if (!more) break;
      node = nn; e0 = ne0; e1 = ne1; di = ndi; sv = nsv;
    }
  }

  atomicAdd(&lsum[f0],     ts0); atomicAdd(&lsum[f0 + 1], ts1);
  atomicAdd(&lssq[f0],     tq0); atomicAdd(&lssq[f0 + 1], tq1);
  __syncthreads();
  if (tid < 128){
    psum[(size_t)blockIdx.x * 128 + tid] = lsum[tid];
    pssq[(size_t)blockIdx.x * 128 + tid] = lssq[tid];
  }
}

// ---------- BN mid-reduction: 2048 partial rows -> 32 (parallelism for the 1MB reduce) ----------
__global__ __launch_bounds__(256) void k_bnmid(const float* __restrict__ psum,
                                               const float* __restrict__ pssq,
                                               float* __restrict__ msum,
                                               float* __restrict__ mssq){
  __shared__ float ss[2][128];
  __shared__ float sq[2][128];
  const int tid = threadIdx.x;
  const int f  = tid & 127;
  const int sl = tid >> 7;
  const int rows_per = AGG_BLOCKS / MID_BLOCKS;  // 64
  const int base = blockIdx.x * rows_per;
  float s = 0.f, q = 0.f;
  for (int r = base + sl; r < base + rows_per; r += 2){
    s += psum[(size_t)r * 128 + f];
    q += pssq[(size_t)r * 128 + f];
  }
  ss[sl][f] = s; sq[sl][f] = q;
  __syncthreads();
  if (tid < 128){
    msum[(size_t)blockIdx.x * 128 + tid] = ss[0][tid] + ss[1][tid];
    mssq[(size_t)blockIdx.x * 128 + tid] = sq[0][tid] + sq[1][tid];
  }
}

// ---------- BN finalize preamble (redundant per block; reads 32 mid rows) ----------
__device__ __forceinline__ void bn_finalize_lds(const float* __restrict__ msum,
                                                const float* __restrict__ mssq,
                                                const float* __restrict__ gamma,
                                                const float* __restrict__ beta,
                                                float* ssc, float* ssh){
  const int tid = threadIdx.x;
  if (tid < 128){
    float S = 0.f, Q = 0.f;
#pragma unroll
    for (int b = 0; b < MID_BLOCKS; b++){
      S += msum[(size_t)b * 128 + tid];
      Q += mssq[(size_t)b * 128 + tid];
    }
    const float inv = 1.0f / (float)ROWS;
    float mu = S * inv;
    float var = fmaxf(Q * inv - mu * mu, 0.f);
    float rstd = 1.0f / sqrtf(var + 1e-5f);
    float sc = gamma[tid] * rstd;
    ssc[tid] = sc;
    ssh[tid] = fmaf(-mu, sc, beta[tid]);
  }
  __syncthreads();
}

// ---------- prep2: BN1-finalize + pack s1(.)W2 + C2 = t1 @ W2 (9 blocks) ----------
__global__ void k_prep2(const float* __restrict__ msum, const float* __restrict__ mssq,
                        const float* __restrict__ gamma, const float* __restrict__ beta,
                        const float* __restrict__ W2,
                        uint16_t* __restrict__ WP2, float* __restrict__ C2){
  __shared__ float ssc[128];
  __shared__ float ssh[128];
  bn_finalize_lds(msum, mssq, gamma, beta, ssc, ssh);
  if (blockIdx.x < 8){
    pack_w(blockIdx.x * 256 + threadIdx.x, W2, ssc, WP2);
  } else if (threadIdx.x < 128){
    const int j = threadIdx.x;
    float a = 0.f;
    for (int k = 0; k < HID; k++) a = fmaf(ssh[k], W2[(size_t)k * HID + j], a);
    C2[j] = a;
  }
}

// ---------- prepc: BN2-finalize + pack s2(.)Wc + CVC = t2 @ Wc + bc (2 blocks) ----------
__global__ void k_prepc(const float* __restrict__ msum, const float* __restrict__ mssq,
                        const float* __restrict__ gamma, const float* __restrict__ beta,
                        const float* __restrict__ Wc, const float* __restrict__ bc,
                        uint16_t* __restrict__ WPC, float* __restrict__ CVC){
  __shared__ float ssc[128];
  __shared__ float ssh[128];
  bn_finalize_lds(msum, mssq, gamma, beta, ssc, ssh);
  if (blockIdx.x == 0){
    // classifier pack: single c-tile, original col mapping
    int t = threadIdx.x;
    int L = t & 63;
    int s = t >> 6;
    int n = L & 15;
    int k0 = s * 32 + (L >> 4) * 8;
    ushort8 r;
#pragma unroll
    for (int j = 0; j < 8; j++)
      r[j] = f2bf(ssc[k0 + j] * Wc[(size_t)(k0 + j) * OUTD + n]);
    *((ushort8*)(WPC + (size_t)t * 8)) = r;
  } else if (threadIdx.x < OUTD){
    const int j = threadIdx.x;
    float a = bc[j];
    for (int k = 0; k < HID; k++) a = fmaf(ssh[k], Wc[(size_t)k * OUTD + j], a);
    CVC[j] = a;
  }
}

// ---------- launch ----------
extern "C" void kernel_launch(void* const* d_in, const int* in_sizes, int n_in,
                              void* d_out, int out_size, void* d_ws, size_t ws_size,
                              hipStream_t stream){
  const float* x   = (const float*)d_in[0];
  const int*   ei  = (const int*)d_in[1];
  const float* ewp = (const float*)d_in[2];
  const float* W1  = (const float*)d_in[3];
  const float* b1  = (const float*)d_in[4];
  const float* W2  = (const float*)d_in[5];
  const float* b2  = (const float*)d_in[6];
  const float* g1  = (const float*)d_in[7];
  const float* be1 = (const float*)d_in[8];
  const float* g2  = (const float*)d_in[9];
  const float* be2 = (const float*)d_in[10];
  const float* Wc  = (const float*)d_in[11];
  const float* bc  = (const float*)d_in[12];
  float* out = (float*)d_out;

  char* wsb = (char*)d_ws;
  size_t off = 0;
  auto give = [&](size_t bytes) -> void* {
    void* p = wsb + off;
    off = (off + bytes + 255) & ~(size_t)255;
    return p;
  };
  uint16_t* XW  = (uint16_t*)give((size_t)ROWS * 128 * 2);   // pair-interleaved [node][pair][b]
  uint16_t* Hb  = (uint16_t*)give((size_t)ROWS * 128 * 2);   // planar
  unsigned long long* DC  = (unsigned long long*)give((size_t)N_NODES * 8);
  unsigned long long* EDG = (unsigned long long*)give((size_t)N_EDGES * 8);
  unsigned int* SLOT = (unsigned int*)give((size_t)N_EDGES * 4);
  float* DINV   = (float*)give((size_t)N_NODES * 4);
  unsigned long long* RP2 = (unsigned long long*)give((size_t)N_NODES * 8);
  unsigned int* CURSOR = (unsigned int*)give(256);
  float* PSUM   = (float*)give((size_t)AGG_BLOCKS * 128 * 4);
  float* PSSQ   = (float*)give((size_t)AGG_BLOCKS * 128 * 4);
  float* MSUM   = (float*)give((size_t)MID_BLOCKS * 128 * 4);
  float* MSSQ   = (float*)give((size_t)MID_BLOCKS * 128 * 4);
  uint16_t* WP1 = (uint16_t*)give((size_t)HID * HID * 2);
  uint16_t* WP2 = (uint16_t*)give((size_t)HID * HID * 2);
  uint16_t* WPC = (uint16_t*)give((size_t)HID * OUTD * 2);
  float* C2     = (float*)give(512);
  float* CVC    = (float*)give(64);
  (void)ws_size; (void)n_in; (void)in_sizes; (void)out_size;

  // 1: zero DC + zero cursor + pack W1
  k_initpack<<<SCAN_BLOCKS + 8, 256, 0, stream>>>(DC, W1, WP1, CURSOR);
  // 2: fused edge atomics (+SLOT) and GEMM1 (overlap, 5:2)
  k_edge_gemm1<<<EG_BLOCKS, 256, 0, stream>>>(ei, ewp, DC, SLOT, x, WP1, XW);
  // 3: dinv + CSR range allocation (single kernel, atomic-bump)
  k_alloc<<<SCAN_BLOCKS, 256, 0, stream>>>(DC, RP2, DINV, CURSOR);
  // 4: CSR fill
  k_fill<<<(N_EDGES + 255) / 256, 256, 0, stream>>>(ei, ewp, DINV, SLOT, RP2, EDG);
  // layer 1 aggregation + BN stats
  k_agg<<<AGG_BLOCKS, 256, 0, stream>>>(XW, RP2, EDG, DINV, b1, nullptr, Hb, PSUM, PSSQ);
  k_bnmid<<<MID_BLOCKS, 256, 0, stream>>>(PSUM, PSSQ, MSUM, MSSQ);
  // BN1-finalize + W2 pack + C2
  k_prep2<<<9, 256, 0, stream>>>(MSUM, MSSQ, g1, be1, W2, WP2, C2);
  // layer 2
  k_gemm2<<<G2_BLOCKS, 256, 0, stream>>>(Hb, WP2, XW);
  k_agg<<<AGG_BLOCKS, 256, 0, stream>>>(XW, RP2, EDG, DINV, b2, C2, Hb, PSUM, PSSQ);
  k_bnmid<<<MID_BLOCKS, 256, 0, stream>>>(PSUM, PSSQ, MSUM, MSSQ);
  // BN2-finalize + Wc pack + CVC
  k_prepc<<<2, 256, 0, stream>>>(MSUM, MSSQ, g2, be2, Wc, bc, WPC, CVC);
  // classifier
  k_cls_mfma<<<GEMM_BLOCKS, 256, 0, stream>>>(Hb, WPC, CVC, out);
}

// Round 11
// 309.563 us; speedup vs baseline: 1.0634x; 1.0634x over previous
//
#include <hip/hip_runtime.h>
#include <hip/hip_bf16.h>
#include <cstdint>
#include <cstddef>

#define N_NODES 50000
#define N_EDGES 640000
#define ROWS    100000   // B * N_NODES
#define HID     128
#define OUTD    16
#define AGG_BLOCKS 2048
#define MID_BLOCKS 32
#define SCAN_BLOCKS 196  // ceil(50000/256)
#define GEMM_BLOCKS 512
#define G2_BLOCKS   400           // 1600 waves, ~2 pair-tiles each: wf (32KB/wave) amortized 2x
#define GEMM_TILES  (ROWS / 16)   // 6250
#define PAIR_TILES  (N_NODES / 16) // 3125 (batch-0 tile + its batch-1 twin)
#define EG_BLOCKS   3500          // fused edge(2500) + gemm1(1000), 5:2 interleave
#define EG_GEMM_WAVES 4000        // 1000 blocks * 4 waves

// ---------- types ----------
typedef __attribute__((ext_vector_type(8))) uint16_t ushort8;
typedef __attribute__((ext_vector_type(8))) __bf16   bf16x8;
typedef __attribute__((ext_vector_type(2))) __bf16   bf16x2;
typedef __attribute__((ext_vector_type(4))) float    floatx4;

union FragU { ushort8 u; bf16x8 b; };

// ---------- bf16 helpers ----------
__device__ __forceinline__ float bf_lo(uint32_t u){
  union { uint32_t u; float f; } c; c.u = u << 16; return c.f;
}
__device__ __forceinline__ float bf_hi(uint32_t u){
  union { uint32_t u; float f; } c; c.u = u & 0xffff0000u; return c.f;
}
__device__ __forceinline__ uint16_t f2bf(float f){   // RNE bit-twiddle (cold paths)
  union { float f; uint32_t u; } c; c.f = f;
  uint32_t u = c.u;
  uint32_t r = (u + 0x7fffu + ((u >> 16) & 1u)) >> 16;
  return (uint16_t)r;
}
// native-cast pack (hot paths): compiler emits packed cvt; RNE, bit-identical to f2bf
__device__ __forceinline__ uint32_t pkbf(float a, float b){
  union { bf16x2 v; uint32_t u; } c;
  c.v[0] = (__bf16)a; c.v[1] = (__bf16)b;
  return c.u;
}

// ---------- W pack (paired-column B-frag mapping), shared by initpack/prep2 ----------
// c-tile c, in-tile col m -> actual col (c>>1)*32 + 2m + (c&1)  (adjacent-col acc pairs)
__device__ __forceinline__ void pack_w(int t, const float* __restrict__ W,
                                       const float* sca /*LDS or null*/,
                                       uint16_t* __restrict__ WP){
  int L = t & 63;
  int s = (t >> 6) & 3;
  int c = t >> 8;
  int n = (c >> 1) * 32 + 2 * (L & 15) + (c & 1);
  int k0 = s * 32 + (L >> 4) * 8;
  ushort8 r;
#pragma unroll
  for (int j = 0; j < 8; j++){
    float w = W[(size_t)(k0 + j) * HID + n];
    if (sca) w *= sca[k0 + j];
    r[j] = f2bf(w);
  }
  *((ushort8*)(WP + (size_t)t * 8)) = r;
}

// ---------- launch 1: zero DC + zero cursor + pack W1 ----------
__global__ void k_initpack(unsigned long long* __restrict__ dc,
                           const float* __restrict__ W1, uint16_t* __restrict__ WP1,
                           unsigned int* __restrict__ cursor){
  int b = blockIdx.x;
  if (b < SCAN_BLOCKS){
    int i = b * 256 + threadIdx.x;
    if (i < N_NODES) dc[i] = 0ull;
  } else {
    if (b == SCAN_BLOCKS && threadIdx.x == 0) *cursor = 0u;
    pack_w((b - SCAN_BLOCKS) * 256 + threadIdx.x, W1, nullptr, WP1);
  }
}

// ---------- launch 2: fused edge-degree atomics + GEMM1 (independent, overlap; 5:2) ----------
// DC[i]: bits[63:44] = in-degree count, bits[43:0] = sum(w) in 2^20 fixed point.
// NOTE: launch_bounds min-waves MUST stay 2 — min 4 caps VGPR at 128 and spills wf[8][4]
// XW layout: PAIR-INTERLEAVED — u32 index = node*128 + p*2 + b (p = feature-pair 0..63).
__global__ __launch_bounds__(256, 2) void k_edge_gemm1(const int* __restrict__ ei,
                                                       const float* __restrict__ ewp,
                                                       unsigned long long* __restrict__ dc,
                                                       unsigned int* __restrict__ slot,
                                                       const float* __restrict__ X,
                                                       const uint16_t* __restrict__ WP,
                                                       uint16_t* __restrict__ Y){
  const int b = blockIdx.x;
  const int g = b % 7;
  if (g < 5){
    // ---- edge part: block eb handles 256 edges ----
    const int eb = (b / 7) * 5 + g;              // 0..2499
    const int e = eb * 256 + threadIdx.x;        // < 640000 exactly
    float w = expf(ewp[e]);
    int c = ei[N_EDGES + e];
    unsigned long long inc = (1ull << 44) | (unsigned long long)(w * 1048576.0f + 0.5f);
    unsigned long long old = atomicAdd(&dc[c], inc);
    slot[e] = (unsigned int)(old >> 44);
    return;
  }
  // ---- gemm1 part: bf16(x) @ W1' -> XW pair-interleaved, tile-pair per wave ----
  const int lane = threadIdx.x & 63;
  const int wid  = threadIdx.x >> 6;
  const int gw   = ((b / 7) * 2 + (g - 5)) * 4 + wid;   // 0..3999
  if (gw >= PAIR_TILES) return;   // 875/4000 waves have no tile: skip the 32KB wf prologue
  const int m    = lane & 15;
  const int kq   = lane >> 4;

  FragU wf[8][4];
#pragma unroll
  for (int c = 0; c < 8; c++)
#pragma unroll
    for (int s = 0; s < 4; s++)
      wf[c][s].u = *((const ushort8*)(WP + (size_t)(((c * 4 + s) * 64 + lane) * 8)));

  unsigned long long* Yq = (unsigned long long*)Y;
  for (int t = gw; t < PAIR_TILES; t += EG_GEMM_WAVES){
    const int nb = t * 16;                      // node rows nb..nb+15
    uint32_t pr0[16];
    // ---- batch 0 tile ----
    {
      FragU af[4];
#pragma unroll
      for (int s = 0; s < 4; s++){
        const float* p = X + (size_t)(nb + m) * HID + s * 32 + kq * 8;
        floatx4 f0 = *((const floatx4*)p);
        floatx4 f1 = *((const floatx4*)(p + 4));
#pragma unroll
        for (int j = 0; j < 4; j++){ af[s].b[j] = (__bf16)f0[j]; af[s].b[j + 4] = (__bf16)f1[j]; }
      }
      floatx4 acc[8];
#pragma unroll
      for (int c = 0; c < 8; c++) acc[c] = floatx4{0.f, 0.f, 0.f, 0.f};
#pragma unroll
      for (int s = 0; s < 4; s++)
#pragma unroll
        for (int c = 0; c < 8; c++)
          acc[c] = __builtin_amdgcn_mfma_f32_16x16x32_bf16(af[s].b, wf[c][s].b, acc[c], 0, 0, 0);
#pragma unroll
      for (int t4 = 0; t4 < 4; t4++)
#pragma unroll
        for (int i = 0; i < 4; i++)
          pr0[t4 * 4 + i] = pkbf(acc[2 * t4][i], acc[2 * t4 + 1][i]);
    }
    // ---- batch 1 tile (same nodes) + fused u64 store ----
    {
      FragU af[4];
#pragma unroll
      for (int s = 0; s < 4; s++){
        const float* p = X + (size_t)(N_NODES + nb + m) * HID + s * 32 + kq * 8;
        floatx4 f0 = *((const floatx4*)p);
        floatx4 f1 = *((const floatx4*)(p + 4));
#pragma unroll
        for (int j = 0; j < 4; j++){ af[s].b[j] = (__bf16)f0[j]; af[s].b[j + 4] = (__bf16)f1[j]; }
      }
      floatx4 acc[8];
#pragma unroll
      for (int c = 0; c < 8; c++) acc[c] = floatx4{0.f, 0.f, 0.f, 0.f};
#pragma unroll
      for (int s = 0; s < 4; s++)
#pragma unroll
        for (int c = 0; c < 8; c++)
          acc[c] = __builtin_amdgcn_mfma_f32_16x16x32_bf16(af[s].b, wf[c][s].b, acc[c], 0, 0, 0);
#pragma unroll
      for (int t4 = 0; t4 < 4; t4++)
#pragma unroll
        for (int i = 0; i < 4; i++){
          uint32_t pr1 = pkbf(acc[2 * t4][i], acc[2 * t4 + 1][i]);
          Yq[(size_t)(nb + kq * 4 + i) * 64 + t4 * 16 + m] =
              (unsigned long long)pr0[t4 * 4 + i] | ((unsigned long long)pr1 << 32);
        }
    }
  }
}

// ---------- launch 3: DC -> dinv + CSR range allocation (NO ordered scan needed) ----------
__global__ void k_alloc(const unsigned long long* __restrict__ dc,
                        unsigned long long* __restrict__ rp2,
                        float* __restrict__ dinv,
                        unsigned int* __restrict__ cursor){
  __shared__ int sd[256];
  __shared__ unsigned int sbase;
  const int tid = threadIdx.x;
  const int i = blockIdx.x * 256 + tid;
  int cnt = 0;
  if (i < N_NODES){
    unsigned long long v = dc[i];
    cnt = (int)(v >> 44);
    float deg = 1.0f + (float)((double)(v & ((1ull << 44) - 1)) * (1.0 / 1048576.0));
    dinv[i] = 1.0f / sqrtf(deg);
  }
  sd[tid] = cnt;
  __syncthreads();
  for (int off = 1; off < 256; off <<= 1){
    int t = (tid >= off) ? sd[tid - off] : 0;
    __syncthreads();
    sd[tid] += t;
    __syncthreads();
  }
  if (tid == 255) sbase = atomicAdd(cursor, (unsigned int)sd[255]);
  __syncthreads();
  if (i < N_NODES){
    unsigned int start = sbase + (unsigned int)(sd[tid] - cnt);
    rp2[i] = ((unsigned long long)(unsigned int)cnt << 32) | start;
  }
}

// ---------- launch 4: fill CSR with packed record (norm<<32 | src); slot known -> NO atomic ----------
__global__ void k_fill(const int* __restrict__ ei, const float* __restrict__ ewp,
                       const float* __restrict__ dinv, const unsigned int* __restrict__ slot,
                       const unsigned long long* __restrict__ rp2,
                       unsigned long long* __restrict__ edg){
  int e = blockIdx.x * 256 + threadIdx.x;
  if (e < N_EDGES){
    int r = ei[e];
    int c = ei[N_EDGES + e];
    float w = expf(ewp[e]);
    float nrm = dinv[r] * w * dinv[c];
    int p = (int)(unsigned int)rp2[c] + (int)slot[e];
    edg[p] = ((unsigned long long)__float_as_uint(nrm) << 32) | (unsigned int)r;
  }
}

// ---------- standalone GEMM2: bf16 H @ W2' -> XW pair-interleaved, tile-pair per wave ----------
__global__ __launch_bounds__(256, 2) void k_gemm2(const uint16_t* __restrict__ X,
                                                  const uint16_t* __restrict__ WP,
                                                  uint16_t* __restrict__ Y){
  const int lane = threadIdx.x & 63;
  const int wid  = threadIdx.x >> 6;
  const int gw   = blockIdx.x * 4 + wid;
  const int nw   = G2_BLOCKS * 4;
  const int m    = lane & 15;
  const int kq   = lane >> 4;

  FragU wf[8][4];
#pragma unroll
  for (int c = 0; c < 8; c++)
#pragma unroll
    for (int s = 0; s < 4; s++)
      wf[c][s].u = *((const ushort8*)(WP + (size_t)(((c * 4 + s) * 64 + lane) * 8)));

  unsigned long long* Yq = (unsigned long long*)Y;
  for (int t = gw; t < PAIR_TILES; t += nw){
    const int nb = t * 16;
    uint32_t pr0[16];
    // ---- batch 0 tile ----
    {
      FragU af[4];
#pragma unroll
      for (int s = 0; s < 4; s++)
        af[s].u = *((const ushort8*)(X + (size_t)(nb + m) * HID + s * 32 + kq * 8));
      floatx4 acc[8];
#pragma unroll
      for (int c = 0; c < 8; c++) acc[c] = floatx4{0.f, 0.f, 0.f, 0.f};
#pragma unroll
      for (int s = 0; s < 4; s++)
#pragma unroll
        for (int c = 0; c < 8; c++)
          acc[c] = __builtin_amdgcn_mfma_f32_16x16x32_bf16(af[s].b, wf[c][s].b, acc[c], 0, 0, 0);
#pragma unroll
      for (int t4 = 0; t4 < 4; t4++)
#pragma unroll
        for (int i = 0; i < 4; i++)
          pr0[t4 * 4 + i] = pkbf(acc[2 * t4][i], acc[2 * t4 + 1][i]);
    }
    // ---- batch 1 tile + fused u64 store ----
    {
      FragU af[4];
#pragma unroll
      for (int s = 0; s < 4; s++)
        af[s].u = *((const ushort8*)(X + (size_t)(N_NODES + nb + m) * HID + s * 32 + kq * 8));
      floatx4 acc[8];
#pragma unroll
      for (int c = 0; c < 8; c++) acc[c] = floatx4{0.f, 0.f, 0.f, 0.f};
#pragma unroll
      for (int s = 0; s < 4; s++)
#pragma unroll
        for (int c = 0; c < 8; c++)
          acc[c] = __builtin_amdgcn_mfma_f32_16x16x32_bf16(af[s].b, wf[c][s].b, acc[c], 0, 0, 0);
#pragma unroll
      for (int t4 = 0; t4 < 4; t4++)
#pragma unroll
        for (int i = 0; i < 4; i++){
          uint32_t pr1 = pkbf(acc[2 * t4][i], acc[2 * t4 + 1][i]);
          Yq[(size_t)(nb + kq * 4 + i) * 64 + t4 * 16 + m] =
              (unsigned long long)pr0[t4 * 4 + i] | ((unsigned long long)pr1 << 32);
        }
    }
  }
}

// ---------- MFMA classifier: out = h @ WcS + cvec (fp32 out) ----------
__global__ __launch_bounds__(256) void k_cls_mfma(const uint16_t* __restrict__ H,
                                                  const uint16_t* __restrict__ WPC,
                                                  const float* __restrict__ cvec,
                                                  float* __restrict__ out){
  const int lane = threadIdx.x & 63;
  const int wid  = threadIdx.x >> 6;
  const int gw   = blockIdx.x * 4 + wid;
  const int nw   = GEMM_BLOCKS * 4;
  const int m    = lane & 15;
  const int kq   = lane >> 4;

  FragU wf[4];
#pragma unroll
  for (int s = 0; s < 4; s++)
    wf[s].u = *((const ushort8*)(WPC + (size_t)((s * 64 + lane) * 8)));
  const float cv = cvec[m];

  for (int t = gw; t < GEMM_TILES; t += nw){
    const int row0 = t * 16;
    FragU af[4];
#pragma unroll
    for (int s = 0; s < 4; s++)
      af[s].u = *((const ushort8*)(H + (size_t)(row0 + m) * HID + s * 32 + kq * 8));
    floatx4 acc = floatx4{0.f, 0.f, 0.f, 0.f};
#pragma unroll
    for (int s = 0; s < 4; s++)
      acc = __builtin_amdgcn_mfma_f32_16x16x32_bf16(af[s].b, wf[s].b, acc, 0, 0, 0);
#pragma unroll
    for (int i = 0; i < 4; i++)
      out[(size_t)(row0 + kq * 4 + i) * OUTD + m] = acc[i] + cv;
  }
}

// ---------- aggregation: node per wave, both batches via ONE dwordx2 gather per edge
// (XW pair-interleaved), edge records loaded LATERALLY (lane u holds rec[e+u])
// + readlane broadcast; rec load for group g+1 (incl. next node's first group)
// issues before group g's gathers. rp2 = {count<<32|start} (one load per node).
// FROZEN at this structure (54us, VGPR 32, occ 66%): r0 request-halving, r8
// working-set-halving, r10 2-deep pipeline (VGPR 52 -> occ 38%, +13%) all failed. ----------
__global__ __launch_bounds__(256) void k_agg(const uint16_t* __restrict__ XW,
                                             const unsigned long long* __restrict__ rp2,
                                             const unsigned long long* __restrict__ edg,
                                             const float* __restrict__ dinv,
                                             const float* __restrict__ bias,
                                             const float* __restrict__ cvec,
                                             uint16_t* __restrict__ H,
                                             float* __restrict__ psum,
                                             float* __restrict__ pssq){
  __shared__ float lsum[128];
  __shared__ float lssq[128];
  const int tid = threadIdx.x;
  if (tid < 128){ lsum[tid] = 0.f; lssq[tid] = 0.f; }
  __syncthreads();

  const int lane = tid & 63;
  const int wid  = tid >> 6;
  const int gw   = blockIdx.x * 4 + wid;
  const int nw   = AGG_BLOCKS * 4;
  const unsigned long long* Xq = (const unsigned long long*)XW;  // [node][pair]: lo u32 = batch0, hi = batch1
  uint32_t* Hu = (uint32_t*)H;
  const int f0 = lane * 2;
  const float b0 = bias[f0], b1 = bias[f0 + 1];
  const float c0 = cvec ? cvec[f0] : 0.f;
  const float c1 = cvec ? cvec[f0 + 1] : 0.f;
  float ts0 = 0.f, ts1 = 0.f, tq0 = 0.f, tq1 = 0.f;
  const int lu = lane & 7;

  int node = gw;
  if (node < N_NODES){
    unsigned long long rc = rp2[node];
    int e0 = (int)(unsigned int)rc, e1 = e0 + (int)(rc >> 32);
    float di = dinv[node];
    unsigned long long sv = Xq[(size_t)node * 64 + lane];
    unsigned long long rec = 0ull;
    if (e0 < e1){
      int a = e0 + lu; if (a > N_EDGES - 1) a = N_EDGES - 1;
      rec = edg[a];
    }
    while (true){
      // prefetch next node's header while this node's edges stream
      const int nn = node + nw;
      const bool more = (nn < N_NODES);
      int ne0 = 0, ne1 = 0; float ndi = 0.f; unsigned long long nsv = 0ull;
      if (more){
        unsigned long long nrc = rp2[nn];
        ne0 = (int)(unsigned int)nrc; ne1 = ne0 + (int)(nrc >> 32);
        ndi = dinv[nn];
        nsv = Xq[(size_t)nn * 64 + lane];
      }

      const float sn = di * di;
      const uint32_t s0 = (uint32_t)sv, s1 = (uint32_t)(sv >> 32);
      float a0x = sn * bf_lo(s0), a0y = sn * bf_hi(s0);
      float a1x = sn * bf_lo(s1), a1y = sn * bf_hi(s1);
      float wsum = sn;

      for (int e = e0; e < e1; e += 8){
        const int r = e1 - e;                    // >= 1; full group iff r >= 8
        const uint32_t rlo = (uint32_t)rec;
        const uint32_t rhi = (uint32_t)(rec >> 32);
        // pipeline: issue the NEXT rec-group load (same node, or next node's first group)
        const int pe = (r > 8) ? (e + 8) : (more ? ne0 : -1);
        if (pe >= 0){
          int a = pe + lu; if (a > N_EDGES - 1) a = N_EDGES - 1;
          rec = edg[a];
        }
        unsigned long long q[8];
        if (r >= 8){
#pragma unroll
          for (int u = 0; u < 8; u++)
            q[u] = Xq[(size_t)(uint32_t)__builtin_amdgcn_readlane((int)rlo, u) * 64 + lane];
#pragma unroll
          for (int u = 0; u < 8; u++){
            const float w = __uint_as_float((uint32_t)__builtin_amdgcn_readlane((int)rhi, u));
            const uint32_t g0 = (uint32_t)q[u], g1 = (uint32_t)(q[u] >> 32);
            a0x = fmaf(w, bf_lo(g0), a0x); a0y = fmaf(w, bf_hi(g0), a0y);
            a1x = fmaf(w, bf_lo(g1), a1x); a1y = fmaf(w, bf_hi(g1), a1y);
            wsum += w;
          }
        } else {
          // predicated tail: r in 1..7, guards are wave-uniform (r uniform)
#pragma unroll
          for (int u = 0; u < 8; u++)
            if (u < r)
              q[u] = Xq[(size_t)(uint32_t)__builtin_amdgcn_readlane((int)rlo, u) * 64 + lane];
#pragma unroll
          for (int u = 0; u < 8; u++)
            if (u < r){
              const float w = __uint_as_float((uint32_t)__builtin_amdgcn_readlane((int)rhi, u));
              const uint32_t g0 = (uint32_t)q[u], g1 = (uint32_t)(q[u] >> 32);
              a0x = fmaf(w, bf_lo(g0), a0x); a0y = fmaf(w, bf_hi(g0), a0y);
              a1x = fmaf(w, bf_lo(g1), a1x); a1y = fmaf(w, bf_hi(g1), a1y);
              wsum += w;
            }
        }
      }
      // zero-edge node: the edge loop never ran, so chain the prefetch here
      if (e0 == e1 && more){
        int a = ne0 + lu; if (a > N_EDGES - 1) a = N_EDGES - 1;
        rec = edg[a];
      }

      // rank-1 BN-fold term + bias + relu
      a0x = fmaxf(fmaf(wsum, c0, a0x) + b0, 0.f); a0y = fmaxf(fmaf(wsum, c1, a0y) + b1, 0.f);
      a1x = fmaxf(fmaf(wsum, c0, a1x) + b0, 0.f); a1y = fmaxf(fmaf(wsum, c1, a1y) + b1, 0.f);
      Hu[(size_t)node * 64 + lane]             = pkbf(a0x, a0y);
      Hu[(size_t)(N_NODES + node) * 64 + lane] = pkbf(a1x, a1y);
      ts0 += a0x + a1x; ts1 += a0y + a1y;
      tq0 += a0x * a0x + a1x * a1x; tq1 += a0y * a0y + a1y * a1y;

      if (!more) break;
      node = nn; e0 = ne0; e1 = ne1; di = ndi; sv = nsv;
    }
  }

  atomicAdd(&lsum[f0],     ts0); atomicAdd(&lsum[f0 + 1], ts1);
  atomicAdd(&lssq[f0],     tq0); atomicAdd(&lssq[f0 + 1], tq1);
  __syncthreads();
  if (tid < 128){
    psum[(size_t)blockIdx.x * 128 + tid] = lsum[tid];
    pssq[(size_t)blockIdx.x * 128 + tid] = lssq[tid];
  }
}

// ---------- BN mid-reduction: 2048 partial rows -> 32 (parallelism for the 1MB reduce) ----------
__global__ __launch_bounds__(256) void k_bnmid(const float* __restrict__ psum,
                                               const float* __restrict__ pssq,
                                               float* __restrict__ msum,
                                               float* __restrict__ mssq){
  __shared__ float ss[2][128];
  __shared__ float sq[2][128];
  const int tid = threadIdx.x;
  const int f  = tid & 127;
  const int sl = tid >> 7;
  const int rows_per = AGG_BLOCKS / MID_BLOCKS;  // 64
  const int base = blockIdx.x * rows_per;
  float s = 0.f, q = 0.f;
  for (int r = base + sl; r < base + rows_per; r += 2){
    s += psum[(size_t)r * 128 + f];
    q += pssq[(size_t)r * 128 + f];
  }
  ss[sl][f] = s; sq[sl][f] = q;
  __syncthreads();
  if (tid < 128){
    msum[(size_t)blockIdx.x * 128 + tid] = ss[0][tid] + ss[1][tid];
    mssq[(size_t)blockIdx.x * 128 + tid] = sq[0][tid] + sq[1][tid];
  }
}

// ---------- BN finalize preamble (redundant per block; reads 32 mid rows) ----------
__device__ __forceinline__ void bn_finalize_lds(const float* __restrict__ msum,
                                                const float* __restrict__ mssq,
                                                const float* __restrict__ gamma,
                                                const float* __restrict__ beta,
                                                float* ssc, float* ssh){
  const int tid = threadIdx.x;
  if (tid < 128){
    float S = 0.f, Q = 0.f;
#pragma unroll
    for (int b = 0; b < MID_BLOCKS; b++){
      S += msum[(size_t)b * 128 + tid];
      Q += mssq[(size_t)b * 128 + tid];
    }
    const float inv = 1.0f / (float)ROWS;
    float mu = S * inv;
    float var = fmaxf(Q * inv - mu * mu, 0.f);
    float rstd = 1.0f / sqrtf(var + 1e-5f);
    float sc = gamma[tid] * rstd;
    ssc[tid] = sc;
    ssh[tid] = fmaf(-mu, sc, beta[tid]);
  }
  __syncthreads();
}

// ---------- prep2: BN1-finalize + pack s1(.)W2 + C2 = t1 @ W2 (9 blocks) ----------
__global__ void k_prep2(const float* __restrict__ msum, const float* __restrict__ mssq,
                        const float* __restrict__ gamma, const float* __restrict__ beta,
                        const float* __restrict__ W2,
                        uint16_t* __restrict__ WP2, float* __restrict__ C2){
  __shared__ float ssc[128];
  __shared__ float ssh[128];
  bn_finalize_lds(msum, mssq, gamma, beta, ssc, ssh);
  if (blockIdx.x < 8){
    pack_w(blockIdx.x * 256 + threadIdx.x, W2, ssc, WP2);
  } else if (threadIdx.x < 128){
    const int j = threadIdx.x;
    float a = 0.f;
    for (int k = 0; k < HID; k++) a = fmaf(ssh[k], W2[(size_t)k * HID + j], a);
    C2[j] = a;
  }
}

// ---------- prepc: BN2-finalize + pack s2(.)Wc + CVC = t2 @ Wc + bc (2 blocks) ----------
__global__ void k_prepc(const float* __restrict__ msum, const float* __restrict__ mssq,
                        const float* __restrict__ gamma, const float* __restrict__ beta,
                        const float* __restrict__ Wc, const float* __restrict__ bc,
                        uint16_t* __restrict__ WPC, float* __restrict__ CVC){
  __shared__ float ssc[128];
  __shared__ float ssh[128];
  bn_finalize_lds(msum, mssq, gamma, beta, ssc, ssh);
  if (blockIdx.x == 0){
    // classifier pack: single c-tile, original col mapping
    int t = threadIdx.x;
    int L = t & 63;
    int s = t >> 6;
    int n = L & 15;
    int k0 = s * 32 + (L >> 4) * 8;
    ushort8 r;
#pragma unroll
    for (int j = 0; j < 8; j++)
      r[j] = f2bf(ssc[k0 + j] * Wc[(size_t)(k0 + j) * OUTD + n]);
    *((ushort8*)(WPC + (size_t)t * 8)) = r;
  } else if (threadIdx.x < OUTD){
    const int j = threadIdx.x;
    float a = bc[j];
    for (int k = 0; k < HID; k++) a = fmaf(ssh[k], Wc[(size_t)k * OUTD + j], a);
    CVC[j] = a;
  }
}

// ---------- launch ----------
extern "C" void kernel_launch(void* const* d_in, const int* in_sizes, int n_in,
                              void* d_out, int out_size, void* d_ws, size_t ws_size,
                              hipStream_t stream){
  const float* x   = (const float*)d_in[0];
  const int*   ei  = (const int*)d_in[1];
  const float* ewp = (const float*)d_in[2];
  const float* W1  = (const float*)d_in[3];
  const float* b1  = (const float*)d_in[4];
  const float* W2  = (const float*)d_in[5];
  const float* b2  = (const float*)d_in[6];
  const float* g1  = (const float*)d_in[7];
  const float* be1 = (const float*)d_in[8];
  const float* g2  = (const float*)d_in[9];
  const float* be2 = (const float*)d_in[10];
  const float* Wc  = (const float*)d_in[11];
  const float* bc  = (const float*)d_in[12];
  float* out = (float*)d_out;

  char* wsb = (char*)d_ws;
  size_t off = 0;
  auto give = [&](size_t bytes) -> void* {
    void* p = wsb + off;
    off = (off + bytes + 255) & ~(size_t)255;
    return p;
  };
  uint16_t* XW  = (uint16_t*)give((size_t)ROWS * 128 * 2);   // pair-interleaved [node][pair][b]
  uint16_t* Hb  = (uint16_t*)give((size_t)ROWS * 128 * 2);   // planar
  unsigned long long* DC  = (unsigned long long*)give((size_t)N_NODES * 8);
  unsigned long long* EDG = (unsigned long long*)give((size_t)N_EDGES * 8);
  unsigned int* SLOT = (unsigned int*)give((size_t)N_EDGES * 4);
  float* DINV   = (float*)give((size_t)N_NODES * 4);
  unsigned long long* RP2 = (unsigned long long*)give((size_t)N_NODES * 8);
  unsigned int* CURSOR = (unsigned int*)give(256);
  float* PSUM   = (float*)give((size_t)AGG_BLOCKS * 128 * 4);
  float* PSSQ   = (float*)give((size_t)AGG_BLOCKS * 128 * 4);
  float* MSUM   = (float*)give((size_t)MID_BLOCKS * 128 * 4);
  float* MSSQ   = (float*)give((size_t)MID_BLOCKS * 128 * 4);
  uint16_t* WP1 = (uint16_t*)give((size_t)HID * HID * 2);
  uint16_t* WP2 = (uint16_t*)give((size_t)HID * HID * 2);
  uint16_t* WPC = (uint16_t*)give((size_t)HID * OUTD * 2);
  float* C2     = (float*)give(512);
  float* CVC    = (float*)give(64);
  (void)ws_size; (void)n_in; (void)in_sizes; (void)out_size;

  // 1: zero DC + zero cursor + pack W1
  k_initpack<<<SCAN_BLOCKS + 8, 256, 0, stream>>>(DC, W1, WP1, CURSOR);
  // 2: fused edge atomics (+SLOT) and GEMM1 (overlap, 5:2)
  k_edge_gemm1<<<EG_BLOCKS, 256, 0, stream>>>(ei, ewp, DC, SLOT, x, WP1, XW);
  // 3: dinv + CSR range allocation (single kernel, atomic-bump)
  k_alloc<<<SCAN_BLOCKS, 256, 0, stream>>>(DC, RP2, DINV, CURSOR);
  // 4: CSR fill
  k_fill<<<(N_EDGES + 255) / 256, 256, 0, stream>>>(ei, ewp, DINV, SLOT, RP2, EDG);
  // layer 1 aggregation + BN stats
  k_agg<<<AGG_BLOCKS, 256, 0, stream>>>(XW, RP2, EDG, DINV, b1, nullptr, Hb, PSUM, PSSQ);
  k_bnmid<<<MID_BLOCKS, 256, 0, stream>>>(PSUM, PSSQ, MSUM, MSSQ);
  // BN1-finalize + W2 pack + C2
  k_prep2<<<9, 256, 0, stream>>>(MSUM, MSSQ, g1, be1, W2, WP2, C2);
  // layer 2
  k_gemm2<<<G2_BLOCKS, 256, 0, stream>>>(Hb, WP2, XW);
  k_agg<<<AGG_BLOCKS, 256, 0, stream>>>(XW, RP2, EDG, DINV, b2, C2, Hb, PSUM, PSSQ);
  k_bnmid<<<MID_BLOCKS, 256, 0, stream>>>(PSUM, PSSQ, MSUM, MSSQ);
  // BN2-finalize + Wc pack + CVC
  k_prepc<<<2, 256, 0, stream>>>(MSUM, MSSQ, g2, be2, Wc, bc, WPC, CVC);
  // classifier
  k_cls_mfma<<<GEMM_BLOCKS, 256, 0, stream>>>(Hb, WPC, CVC, out);
}